// Round 7
// baseline (13487.305 us; speedup 1.0000x reference)
//
#include <hip/hip_runtime.h>
#include <math.h>

// ReservoirLayer: B=8, T=4096, R=1024, F=64, I=32
#define TT 4096
#define RR 1024
#define FF 64
#define II 32
#define GROUPS 8                 // one group per batch element
#define BPG 32                   // ranks per group (h is 32x32 rows)
#define GPB 2                    // groups time-multiplexed per block
#define NBLK (BPG * GROUPS / GPB) // 128 blocks
#define THREADS 256
#define KV4 32                   // float4 of W_hh per thread
#define ALPHA 0.9f
#define TCH 32                   // timesteps per prologue block

typedef unsigned long long u64;
typedef unsigned int u32;
typedef u32 u32x4 __attribute__((ext_vector_type(4)));

#define SLOT_U32 (GROUPS * RR)           // 8192 u32 per parity slot (32 KB)
#define CNT_BASE (2 * SLOT_U32)          // u32 index of per-rank flag area
#define PAD(i) ((i) + (((i) >> 7) << 2)) // +4 floats per 128-float chunk

// Agent-scope (sc1, MALL-coherent) loads.
__device__ __forceinline__ u32x4 ld_agent16(const u32x4* p) {
    u32x4 v;
    asm volatile("global_load_dwordx4 %0, %1, off sc1\n\t"
                 "s_waitcnt vmcnt(0)"
                 : "=v"(v) : "v"(p) : "memory");
    return v;
}
__device__ __forceinline__ u32 ld_agent32(const u32* p) {
    u32 v;
    asm volatile("global_load_dword %0, %1, off sc1\n\t"
                 "s_waitcnt vmcnt(0)"
                 : "=v"(v) : "v"(p) : "memory");
    return v;
}

// Tag-verified read. The flag attests "publish swaps ISSUED" (raw barrier,
// no vmcnt drain); the rare flag-overtakes-data window is bounded by the
// tag spin (data swaps issue before the flag; MALL arrival near-FIFO).
__device__ __forceinline__ u32x4 poll4(const u32x4* p, u32 wtag) {
    u32x4 v = ld_agent16(p);
    while ((((v[0] ^ wtag) | (v[1] ^ wtag) | (v[2] ^ wtag) | (v[3] ^ wtag)) & 1u) != 0u)
        v = ld_agent16(p);
    return v;
}

// Publish via atomic swap (relaxed, agent, result unused): executed AT the
// MALL, cannot linger in per-CU write buffering (rounds 0->2 proved this
// beats plain sc1 stores). 64-bit packs two rows (4096 atomics/step).
__device__ __forceinline__ void st_pub64(u64* p, u64 v) {
    (void)__hip_atomic_exchange(p, v, __ATOMIC_RELAXED, __HIP_MEMORY_SCOPE_AGENT);
}
// Per-rank attest flag swap: each block writes its OWN dword (32 distinct
// dwords on 2 lines -> pipelined at the MALL, no RMW chain — round-5 win).
__device__ __forceinline__ void st_pub32(u32* p, u32 v) {
    (void)__hip_atomic_exchange(p, v, __ATOMIC_RELAXED, __HIP_MEMORY_SCOPE_AGENT);
}

// tanh via v_exp_f32: (e^{2|x|}-1)/(e^{2|x|}+1), |x| clamped at 10.
__device__ __forceinline__ float fast_tanh(float x) {
    float ax = fabsf(x);
    float e  = __expf(2.0f * fminf(ax, 10.0f));
    float r  = (e - 1.0f) * __builtin_amdgcn_rcpf(e + 1.0f);
    return x < 0.0f ? -r : r;
}

// ---------------- Prologue: drive[b,t,r] = fb·W_fb^T + dr·W_in^T -> out ----
// out row t is consumed (as drive) at step t and only overwritten (with h)
// at step t+1 — safe in-place dataflow. Bias added in the main kernel.
__global__ __launch_bounds__(256, 1)
void drive_pre(const float* __restrict__ feedback,
               const float* __restrict__ driving,
               const float* __restrict__ W_fb,
               const float* __restrict__ W_in,
               float* __restrict__ out)
{
    const int tid = threadIdx.x;
    const int b   = blockIdx.x >> 7;            // 128 chunks per batch
    const int t0  = (blockIdx.x & 127) * TCH;

    __shared__ float xch[TCH][96];              // [t][ fb(64) | dr(32) ]

    const float4* fb4 = (const float4*)(feedback + ((size_t)b * TT + t0) * FF);
    #pragma unroll
    for (int q = 0; q < 2; q++) {
        int i = tid + 256 * q;                  // 0..511 : 32t x 16 float4
        float4 v = fb4[i];
        *(float4*)&xch[i >> 4][(i & 15) << 2] = v;
    }
    {
        const float4* dr4 = (const float4*)(driving + ((size_t)b * TT + t0) * II);
        float4 v = dr4[tid];                    // 0..255 : 32t x 8 float4
        *(float4*)&xch[tid >> 3][64 + ((tid & 7) << 2)] = v;
    }
    __syncthreads();

    #pragma unroll 1
    for (int p = 0; p < 4; p++) {
        const int r = p * 256 + tid;
        float4 w[24];
        const float4* wf4 = (const float4*)(W_fb + (size_t)r * FF);
        #pragma unroll
        for (int q = 0; q < 16; q++) w[q] = wf4[q];
        const float4* wi4 = (const float4*)(W_in + (size_t)r * II);
        #pragma unroll
        for (int q = 0; q < 8; q++) w[16 + q] = wi4[q];

        for (int t = 0; t < TCH; t++) {
            float s = 0.0f;
            #pragma unroll
            for (int q = 0; q < 24; q++) {
                float4 x = *(const float4*)&xch[t][q << 2]; // broadcast read
                s = fmaf(w[q].x, x.x, s);
                s = fmaf(w[q].y, x.y, s);
                s = fmaf(w[q].z, x.z, s);
                s = fmaf(w[q].w, x.w, s);
            }
            out[((size_t)b * TT + (t0 + t)) * RR + r] = s;   // coalesced
        }
    }
}

// ---------------- Main recurrence -----------------------------------------
// GPB=2 time-multiplex: each block serves rank `rank` of TWO groups and
// alternates half-steps A,B,A,B... While group A's publishes propagate
// through the MALL (the ~2600cy wait that dominated rounds 3-6), the block
// executes group B's half-step — the wait is hidden behind real work.
// W_hh is SHARED across groups: same w4 registers serve both chains.
// Per-half-step handshake is byte-identical to round 6:
//   publish 16x atomic_swap_x2 (LSB-tagged) -> raw s_barrier (issued, not
//   drained) -> tid64 swaps flag[g][rank]=t+1; next visit: wave0 polls the
//   group's 32 flags (2 lines) __all(>=t), B1, one-shot tag-verified read.
// Slot-reuse induction per group unchanged (flag=t only after this block's
// poll4-read of h_{t-1} completed through LDS stage + B2 + raw B3).
__global__ __launch_bounds__(THREADS, 1)
void reservoir_df(const float* __restrict__ W_hh,
                  const float* __restrict__ bias,
                  float* __restrict__ out,
                  u32* __restrict__ hbuf)
{
    const int tid  = threadIdx.x;
    const int bid  = blockIdx.x;
    const int gp   = bid & 3;              // group-pair index 0..3
    const int rank = bid >> 2;             // 0..31 within each group
    const int lr   = tid >> 3;             // local row 0..31
    const int j    = tid & 7;              // k-slice within row
    const int row  = rank * 32 + lr;

    // W_hh slice: k in [j*128, j*128+128) — shared by both groups
    float4 w4[KV4];
    {
        const float4* whh4 = (const float4*)(W_hh + (size_t)row * RR);
        #pragma unroll
        for (int i = 0; i < KV4; i++) w4[i] = whh4[j * KV4 + i];
    }
    const float brow = bias[row];

    __shared__ float hlds[GPB][2][1056];   // per-group padded h tile x parity

    // Per-group state (gi statically unrolled -> registers, no scratch)
    float*     outg[GPB];
    u32*       myflag[GPB];
    const u32* pollbase[GPB];
    float      dreg[GPB];
    #pragma unroll
    for (int gi = 0; gi < GPB; gi++) {
        const int g  = gp * GPB + gi;
        outg[gi]     = out + (size_t)g * TT * RR;
        myflag[gi]   = hbuf + CNT_BASE + (g << 5) + rank;  // 128B/group: 2 lines
        pollbase[gi] = hbuf + CNT_BASE + (g << 5);
        dreg[gi]     = (j == 0) ? outg[gi][row] : 0.0f;    // drive[0][row]
    }

    for (int t = 0; t < TT; t++) {
        const int par = t & 1;

        #pragma unroll
        for (int gi = 0; gi < GPB; gi++) {
            const int g = gp * GPB + gi;

            // ---- E: detect epoch — wave0 reads the group's 32 flags (2 lines)
            if (t > 0 && tid < 64) {
                const u32* fp = pollbase[gi] + (tid & 31);
                u32 v = ld_agent32(fp);
                while (!__all((int)(v >= (u32)t))) v = ld_agent32(fp);
            }

            // ---- A: next-step drive prefetch (issued while wave0 polls;
            // wave0's copy drains under poll4 after B1)
            float dnext = 0.0f;
            if (j == 0 && t + 1 < TT) dnext = outg[gi][(size_t)(t + 1) * RR + row];

            __syncthreads();                            // B1: epoch visible

            // ---- B: one-shot read of h_t (tag-verified; ~always fresh) ----
            const u32x4* sp4 = (const u32x4*)(hbuf + (size_t)par * SLOT_U32 + (size_t)g * RR) + tid;
            const u32x4 hv = poll4(sp4, (u32)((t >> 1) & 1));
            const float f0 = __uint_as_float(hv[0]);
            const float f1 = __uint_as_float(hv[1]);
            const float f2 = __uint_as_float(hv[2]);
            const float f3 = __uint_as_float(hv[3]);

            // ---- C: coalesced out row t-1 (h_t == out[t-1])
            if (t > 0 && lr == rank) {
                *(float4*)(outg[gi] + (size_t)(t - 1) * RR + 4 * tid) =
                    make_float4(f0, f1, f2, f3);
            }

            // ---- D: stage into padded LDS
            *(float4*)&hlds[gi][par][PAD(4 * tid)] = make_float4(f0, f1, f2, f3);

            __syncthreads();                            // B2

            // ---- G: compute (bank-conflict-free j-sliced float4 reads)
            float4 acc = make_float4(0.f, 0.f, 0.f, 0.f);
            const float* hb = &hlds[gi][par][j * 132];
            #pragma unroll
            for (int i = 0; i < KV4; i++) {
                float4 hvv = *(const float4*)(hb + 4 * i);
                acc.x = fmaf(w4[i].x, hvv.x, acc.x);
                acc.y = fmaf(w4[i].y, hvv.y, acc.y);
                acc.z = fmaf(w4[i].z, hvv.z, acc.z);
                acc.w = fmaf(w4[i].w, hvv.w, acc.w);
            }

            float s = (acc.x + acc.y) + (acc.z + acc.w);
            s += __shfl_xor(s, 1, 64);
            s += __shfl_xor(s, 2, 64);
            s += __shfl_xor(s, 4, 64);

            // ---- H: publish h_{t+1}, packed 2 rows per 64-bit atomic swap
            u32 bits = 0u;
            if (j == 0) {
                const float hold = hlds[gi][par][PAD(row)];
                const float pre  = (1.0f - ALPHA) * hold + ALPHA * (s + dreg[gi] + brow);
                const float hnew = fast_tanh(pre);
                bits = (__float_as_uint(hnew) & ~1u) | (u32)(((t + 1) >> 1) & 1);
                dreg[gi] = dnext;
            }
            const u32 partner = __shfl_xor(bits, 8, 64); // row+1 -> even-row lane
            if ((tid & 15) == 0) {                       // rows even: 8B-aligned
                u64* dst = (u64*)(hbuf + (size_t)((t + 1) & 1) * SLOT_U32 + (size_t)g * RR + row);
                st_pub64(dst, (u64)bits | ((u64)partner << 32));
            }

            // ---- B3': raw barrier — swaps ISSUED by all waves (no vmcnt
            // drain; commit RT overlaps the other group's half-step).
            asm volatile("s_barrier" ::: "memory");

            // ---- F: attest from WAVE 1 (keeps the ack off wave0's vmcnt;
            // wave1's next vmcnt-wait is a full half-step away).
            if (tid == 64) st_pub32(myflag[gi], (u32)(t + 1));
        }
    }

    // ---- final out rows TT-1 from h_TT (slot 0, tag (4096>>1)&1 == 0);
    // pure tag-poll (nobody polls flags for h_TT)
    if (lr == rank) {
        #pragma unroll
        for (int gi = 0; gi < GPB; gi++) {
            const int g = gp * GPB + gi;
            const u32x4* sp4 = (const u32x4*)(hbuf + (size_t)g * RR) + tid;
            const u32x4 hv = poll4(sp4, 0u);
            *(float4*)(outg[gi] + (size_t)(TT - 1) * RR + 4 * tid) =
                make_float4(__uint_as_float(hv[0]), __uint_as_float(hv[1]),
                            __uint_as_float(hv[2]), __uint_as_float(hv[3]));
        }
    }
}

extern "C" void kernel_launch(void* const* d_in, const int* in_sizes, int n_in,
                              void* d_out, int out_size, void* d_ws, size_t ws_size,
                              hipStream_t stream) {
    const float* feedback = (const float*)d_in[0];
    const float* driving  = (const float*)d_in[1];
    const float* W_fb     = (const float*)d_in[2];
    const float* W_in     = (const float*)d_in[3];
    const float* W_hh     = (const float*)d_in[4];
    const float* bias     = (const float*)d_in[5];
    float* out = (float*)d_out;

    u32* hbuf = (u32*)d_ws;
    // ws layout: slot0 (32KB) | slot1 (32KB) | per-rank flags (1KB)
    // = 66,560 B total (same footprint as rounds 3-6).
    // Slot 0 = 0x00: tag 0 + h = 0.0f == h_0, readable at t=0.
    // Slot 1 = 0x01: tag 1 != expected 0 at t=1 -> tag spin until real h_1.
    // Flags = 0: readers at t=1 poll until every rank swaps flag=1.
    hipMemsetAsync(d_ws, 0x00, SLOT_U32 * sizeof(u32), stream);
    hipMemsetAsync((char*)d_ws + SLOT_U32 * sizeof(u32), 0x01, SLOT_U32 * sizeof(u32), stream);
    hipMemsetAsync((char*)d_ws + 2 * SLOT_U32 * sizeof(u32), 0x00, 16 * 64, stream);

    // Prologue: materialize drive = fb@W_fb^T + dr@W_in^T into `out`
    // (consumed in-place; same-stream kernels serialize).
    hipLaunchKernelGGL(drive_pre, dim3(GROUPS * (TT / TCH)), dim3(256), 0, stream,
                       feedback, driving, W_fb, W_in, out);

    void* args[] = { (void*)&W_hh, (void*)&bias, (void*)&out, (void*)&hbuf };
    hipError_t ce = hipLaunchCooperativeKernel((const void*)reservoir_df,
                                               dim3(NBLK), dim3(THREADS), args, 0, stream);
    if (ce != hipSuccess) {
        // Fallback: no grid-wide sync used, only intra-group dataflow; at
        // 128 blocks / ~17 KB LDS all blocks co-reside under plain launch.
        hipLaunchKernelGGL(reservoir_df, dim3(NBLK), dim3(THREADS), 0, stream,
                           W_hh, bias, out, hbuf);
    }
}

// Round 11
// 7709.059 us; speedup vs baseline: 1.7495x; 1.7495x over previous
//
#include <hip/hip_runtime.h>
#include <math.h>

// ReservoirLayer: B=8, T=4096, R=1024, F=64, I=32
#define TT 4096
#define RR 1024
#define FF 64
#define II 32
#define GROUPS 8                 // one group per batch element
#define BPG 32                   // blocks per group
#define THREADS 256
#define KV4 32                   // float4 of W_hh per thread
#define ALPHA 0.9f
#define TCH 32                   // timesteps per prologue block

typedef unsigned long long u64;
typedef unsigned int u32;
typedef u32 u32x4 __attribute__((ext_vector_type(4)));

#define SLOT_U32 (GROUPS * RR)           // 8192 u32 per parity slot (32 KB)
#define CNT_BASE (2 * SLOT_U32)          // u32 index of per-rank flag area
#define PAD(i) ((i) + (((i) >> 7) << 2)) // +4 floats per 128-float chunk

// Agent-scope (sc1, MALL-coherent) loads.
__device__ __forceinline__ u32x4 ld_agent16(const u32x4* p) {
    u32x4 v;
    asm volatile("global_load_dwordx4 %0, %1, off sc1\n\t"
                 "s_waitcnt vmcnt(0)"
                 : "=v"(v) : "v"(p) : "memory");
    return v;
}
__device__ __forceinline__ u32 ld_agent32(const u32* p) {
    u32 v;
    asm volatile("global_load_dword %0, %1, off sc1\n\t"
                 "s_waitcnt vmcnt(0)"
                 : "=v"(v) : "v"(p) : "memory");
    return v;
}

// Tag-verified read. The flag attests "publish swaps ISSUED" (raw barrier,
// no vmcnt drain); the rare flag-overtakes-data window is bounded by the
// tag spin (data swaps issue before the flag; MALL arrival near-FIFO).
__device__ __forceinline__ u32x4 poll4(const u32x4* p, u32 wtag) {
    u32x4 v = ld_agent16(p);
    while ((((v[0] ^ wtag) | (v[1] ^ wtag) | (v[2] ^ wtag) | (v[3] ^ wtag)) & 1u) != 0u)
        v = ld_agent16(p);
    return v;
}

// Publish via atomic swap (relaxed, agent, result unused): executed AT the
// MALL, cannot linger in per-CU write buffering (rounds 0->2 proved this
// beats plain sc1 stores). 64-bit packs two rows (4096 atomics/step).
__device__ __forceinline__ void st_pub64(u64* p, u64 v) {
    (void)__hip_atomic_exchange(p, v, __ATOMIC_RELAXED, __HIP_MEMORY_SCOPE_AGENT);
}
// Per-rank attest flag swap: each block writes its OWN dword (32 distinct
// dwords on 2 lines -> pipelined at the MALL, no RMW chain — round-5 win).
__device__ __forceinline__ void st_pub32(u32* p, u32 v) {
    (void)__hip_atomic_exchange(p, v, __ATOMIC_RELAXED, __HIP_MEMORY_SCOPE_AGENT);
}

// tanh via v_exp_f32: (e^{2|x|}-1)/(e^{2|x|}+1), |x| clamped at 10.
__device__ __forceinline__ float fast_tanh(float x) {
    float ax = fabsf(x);
    float e  = __expf(2.0f * fminf(ax, 10.0f));
    float r  = (e - 1.0f) * __builtin_amdgcn_rcpf(e + 1.0f);
    return x < 0.0f ? -r : r;
}

// ---------------- Prologue: drive[b,t,r] = fb·W_fb^T + dr·W_in^T -> out ----
// out row t is consumed (as drive) at step t and only overwritten (with h)
// at step t+1 — safe in-place dataflow. Bias added in the main kernel.
__global__ __launch_bounds__(256, 1)
void drive_pre(const float* __restrict__ feedback,
               const float* __restrict__ driving,
               const float* __restrict__ W_fb,
               const float* __restrict__ W_in,
               float* __restrict__ out)
{
    const int tid = threadIdx.x;
    const int b   = blockIdx.x >> 7;            // 128 chunks per batch
    const int t0  = (blockIdx.x & 127) * TCH;

    __shared__ float xch[TCH][96];              // [t][ fb(64) | dr(32) ]

    const float4* fb4 = (const float4*)(feedback + ((size_t)b * TT + t0) * FF);
    #pragma unroll
    for (int q = 0; q < 2; q++) {
        int i = tid + 256 * q;                  // 0..511 : 32t x 16 float4
        float4 v = fb4[i];
        *(float4*)&xch[i >> 4][(i & 15) << 2] = v;
    }
    {
        const float4* dr4 = (const float4*)(driving + ((size_t)b * TT + t0) * II);
        float4 v = dr4[tid];                    // 0..255 : 32t x 8 float4
        *(float4*)&xch[tid >> 3][64 + ((tid & 7) << 2)] = v;
    }
    __syncthreads();

    #pragma unroll 1
    for (int p = 0; p < 4; p++) {
        const int r = p * 256 + tid;
        float4 w[24];
        const float4* wf4 = (const float4*)(W_fb + (size_t)r * FF);
        #pragma unroll
        for (int q = 0; q < 16; q++) w[q] = wf4[q];
        const float4* wi4 = (const float4*)(W_in + (size_t)r * II);
        #pragma unroll
        for (int q = 0; q < 8; q++) w[16 + q] = wi4[q];

        for (int t = 0; t < TCH; t++) {
            float s = 0.0f;
            #pragma unroll
            for (int q = 0; q < 24; q++) {
                float4 x = *(const float4*)&xch[t][q << 2]; // broadcast read
                s = fmaf(w[q].x, x.x, s);
                s = fmaf(w[q].y, x.y, s);
                s = fmaf(w[q].z, x.z, s);
                s = fmaf(w[q].w, x.w, s);
            }
            out[((size_t)b * TT + (t0 + t)) * RR + r] = s;   // coalesced
        }
    }
}

// ---------------- Main recurrence -----------------------------------------
// Handshake per step t (round-6 protocol, A hoisted above E):
//   step t-1 end: 16x atomic_swap_x2 (h_t rows, LSB-tagged)
//                 raw s_barrier (swaps issued) -> tid64 swaps flag = t
//   step t start: A (dnext HBM prefetch) issued FIRST — its ~900cy latency
//                 drains under wave0's E flag-spin instead of sitting
//                 exposed at B1's implicit vmcnt(0) (round-6 defect: wave0
//                 issued dnext AFTER the E spin, then __syncthreads drained
//                 it serially on the critical path).
//                 E: wave0 polls the group's 32 flags (2 lines) __all(>=t)
//   B1 -> one-shot tag-verified 16B read.
// Slot-reuse induction per group unchanged (rounds 3/5/6).
__global__ __launch_bounds__(THREADS, 1)
void reservoir_df(const float* __restrict__ W_hh,
                  const float* __restrict__ bias,
                  float* __restrict__ out,
                  u32* __restrict__ hbuf)
{
    const int tid  = threadIdx.x;
    const int bid  = blockIdx.x;
    const int g    = bid & 7;              // batch / group
    const int rank = bid >> 3;             // 0..31 within group
    const int lr   = tid >> 3;             // local row 0..31
    const int j    = tid & 7;              // k-slice within row
    const int row  = rank * 32 + lr;

    // W_hh slice: k in [j*128, j*128+128)
    float4 w4[KV4];
    {
        const float4* whh4 = (const float4*)(W_hh + (size_t)row * RR);
        #pragma unroll
        for (int i = 0; i < KV4; i++) w4[i] = whh4[j * KV4 + i];
    }
    const float brow = bias[row];

    __shared__ float hlds[2][1056];        // padded h tile per parity

    float* outg = out + (size_t)g * TT * RR;
    // flag[g][rank] at dword CNT_BASE + g*32 + rank: one group's 32 flags
    // are 128B contiguous = 2 lines (detect reads 2 lines, round-4 lesson)
    u32*       myflag   = hbuf + CNT_BASE + (g << 5) + rank;
    const u32* pollbase = hbuf + CNT_BASE + (g << 5);

    // drive prefetch (publishers only): dreg = drive[t][row], one step ahead
    float dreg = (j == 0) ? outg[row] : 0.0f;

    for (int t = 0; t < TT; t++) {
        const int par = t & 1;

        // ---- A: next-step drive prefetch — issued BEFORE the E spin so the
        // ~900cy HBM latency drains under the flag polls (wave0) or the B1
        // wait (waves 1-3), never exposed at B1's implicit vmcnt(0).
        float dnext = 0.0f;
        if (j == 0 && t + 1 < TT) dnext = outg[(size_t)(t + 1) * RR + row];

        // ---- E: detect epoch — wave0 reads the group's 32 flags (2 lines)
        if (t > 0 && tid < 64) {
            const u32* fp = pollbase + (tid & 31);
            u32 v = ld_agent32(fp);
            while (!__all((int)(v >= (u32)t))) v = ld_agent32(fp);
        }

        __syncthreads();                                // B1: epoch visible

        // ---- B: one-shot read of h_t (tag-verified; ~always fresh) --------
        const u32x4* sp4 = (const u32x4*)(hbuf + (size_t)par * SLOT_U32 + (size_t)g * RR) + tid;
        const u32x4 hv = poll4(sp4, (u32)((t >> 1) & 1));
        const float f0 = __uint_as_float(hv[0]);
        const float f1 = __uint_as_float(hv[1]);
        const float f2 = __uint_as_float(hv[2]);
        const float f3 = __uint_as_float(hv[3]);

        // ---- C: coalesced out row t-1 (h_t == out[t-1]); rank owns 32 cols
        if (t > 0 && lr == rank) {
            *(float4*)(outg + (size_t)(t - 1) * RR + 4 * tid) = make_float4(f0, f1, f2, f3);
        }

        // ---- D: stage into padded LDS
        *(float4*)&hlds[par][PAD(4 * tid)] = make_float4(f0, f1, f2, f3);

        __syncthreads();                                // B2

        // ---- G: compute (bank-conflict-free j-sliced float4 reads)
        float4 acc = make_float4(0.f, 0.f, 0.f, 0.f);
        const float* hb = &hlds[par][j * 132];
        #pragma unroll
        for (int i = 0; i < KV4; i++) {
            float4 hvv = *(const float4*)(hb + 4 * i);
            acc.x = fmaf(w4[i].x, hvv.x, acc.x);
            acc.y = fmaf(w4[i].y, hvv.y, acc.y);
            acc.z = fmaf(w4[i].z, hvv.z, acc.z);
            acc.w = fmaf(w4[i].w, hvv.w, acc.w);
        }

        float s = (acc.x + acc.y) + (acc.z + acc.w);
        s += __shfl_xor(s, 1, 64);
        s += __shfl_xor(s, 2, 64);
        s += __shfl_xor(s, 4, 64);

        // ---- H: publish h_{t+1}, packed 2 rows per 64-bit atomic swap -----
        u32 bits = 0u;
        if (j == 0) {
            const float hold = hlds[par][PAD(row)];
            const float pre  = (1.0f - ALPHA) * hold + ALPHA * (s + dreg + brow);
            const float hnew = fast_tanh(pre);
            bits = (__float_as_uint(hnew) & ~1u) | (u32)(((t + 1) >> 1) & 1);
            dreg = dnext;
        }
        const u32 partner = __shfl_xor(bits, 8, 64);    // row+1 -> even-row lane
        if ((tid & 15) == 0) {                          // rows even: 8B-aligned
            u64* dst = (u64*)(hbuf + (size_t)((t + 1) & 1) * SLOT_U32 + (size_t)g * RR + row);
            st_pub64(dst, (u64)bits | ((u64)partner << 32));
        }

        // ---- B3': raw barrier — swaps ISSUED by all waves (no vmcnt drain)
        asm volatile("s_barrier" ::: "memory");

        // ---- F: attest from WAVE 1 (keeps the ack off wave0's vmcnt;
        // wave1's next vmcnt-wait is a full step away).
        if (tid == 64) st_pub32(myflag, (u32)(t + 1));
    }

    // ---- final out row TT-1 from h_TT (slot 0, tag (4096>>1)&1 == 0);
    // pure tag-poll (nobody polls flags for h_TT)
    if (lr == rank) {
        const u32x4* sp4 = (const u32x4*)(hbuf + (size_t)g * RR) + tid;
        const u32x4 hv = poll4(sp4, 0u);
        *(float4*)(outg + (size_t)(TT - 1) * RR + 4 * tid) =
            make_float4(__uint_as_float(hv[0]), __uint_as_float(hv[1]),
                        __uint_as_float(hv[2]), __uint_as_float(hv[3]));
    }
}

extern "C" void kernel_launch(void* const* d_in, const int* in_sizes, int n_in,
                              void* d_out, int out_size, void* d_ws, size_t ws_size,
                              hipStream_t stream) {
    const float* feedback = (const float*)d_in[0];
    const float* driving  = (const float*)d_in[1];
    const float* W_fb     = (const float*)d_in[2];
    const float* W_in     = (const float*)d_in[3];
    const float* W_hh     = (const float*)d_in[4];
    const float* bias     = (const float*)d_in[5];
    float* out = (float*)d_out;

    u32* hbuf = (u32*)d_ws;
    // ws layout: slot0 (32KB) | slot1 (32KB) | per-rank flags (1KB)
    // = 66,560 B total (same footprint as rounds 3-6).
    // Slot 0 = 0x00: tag 0 + h = 0.0f == h_0, readable at t=0.
    // Slot 1 = 0x01: tag 1 != expected 0 at t=1 -> tag spin until real h_1.
    // Flags = 0: readers at t=1 poll until every rank swaps flag=1.
    (void)hipMemsetAsync(d_ws, 0x00, SLOT_U32 * sizeof(u32), stream);
    (void)hipMemsetAsync((char*)d_ws + SLOT_U32 * sizeof(u32), 0x01, SLOT_U32 * sizeof(u32), stream);
    (void)hipMemsetAsync((char*)d_ws + 2 * SLOT_U32 * sizeof(u32), 0x00, 16 * 64, stream);

    // Prologue: materialize drive = fb@W_fb^T + dr@W_in^T into `out`
    // (consumed in-place; same-stream kernels serialize).
    hipLaunchKernelGGL(drive_pre, dim3(GROUPS * (TT / TCH)), dim3(256), 0, stream,
                       feedback, driving, W_fb, W_in, out);

    void* args[] = { (void*)&W_hh, (void*)&bias, (void*)&out, (void*)&hbuf };
    hipError_t ce = hipLaunchCooperativeKernel((const void*)reservoir_df,
                                               dim3(GROUPS * BPG), dim3(THREADS), args, 0, stream);
    if (ce != hipSuccess) {
        // Fallback: no grid-wide sync used, only intra-group dataflow; at
        // ~90 VGPR / 8.5 KB LDS all 256 blocks co-reside under plain launch.
        hipLaunchKernelGGL(reservoir_df, dim3(GROUPS * BPG), dim3(THREADS), 0, stream,
                           W_hh, bias, out, hbuf);
    }
}